// Round 2
// baseline (612.024 us; speedup 1.0000x reference)
//
#include <hip/hip_runtime.h>
#include <math.h>
#include <stdint.h>
#include <stddef.h>

#define N_NODES 8192
#define N_EDGES 524288
#define N_PAIRS 262144
#define N_TYPES 86
#define F1 128
#define F2 64

// ---------------- degree / CSR build ----------------

__global__ void count_deg_k(const int* __restrict__ dst, int* __restrict__ cnt) {
  int e = blockIdx.x * blockDim.x + threadIdx.x;
  if (e < N_EDGES) atomicAdd(&cnt[dst[e]], 1);
}

__global__ void dinv_k(const int* __restrict__ cnt, float* __restrict__ dinv) {
  int i = blockIdx.x * blockDim.x + threadIdx.x;
  if (i < N_NODES) dinv[i] = 1.0f / sqrtf((float)(cnt[i] + 1)); // +1 self-loop
}

__global__ void scan_k(const int* __restrict__ cnt, int* __restrict__ rp,
                       int* __restrict__ fill) {
  __shared__ int s[1024];
  int t = threadIdx.x;
  int v[8];
  int sum = 0;
#pragma unroll
  for (int i = 0; i < 8; i++) { v[i] = cnt[t * 8 + i]; sum += v[i]; }
  s[t] = sum;
  __syncthreads();
  for (int off = 1; off < 1024; off <<= 1) {
    int add = (t >= off) ? s[t - off] : 0;
    __syncthreads();
    s[t] += add;
    __syncthreads();
  }
  int excl = s[t] - sum;
#pragma unroll
  for (int i = 0; i < 8; i++) {
    rp[t * 8 + i] = excl;
    fill[t * 8 + i] = excl;
    excl += v[i];
  }
  if (t == 1023) rp[N_NODES] = excl;
}

__global__ void scatter_k(const int* __restrict__ src, const int* __restrict__ dst,
                          int* fill, int* __restrict__ csr) {
  int e = blockIdx.x * blockDim.x + threadIdx.x;
  if (e < N_EDGES) {
    int d = dst[e];
    int pos = atomicAdd(&fill[d], 1);
    csr[pos] = src[e];
  }
}

// ---------------- GEMM1: x[8192,8192] @ W1[8192,128], K-split x2 ----------------

#define BM 32
#define BK 64
#define LDA 36  // padded leading dim for transposed A tile

__global__ __launch_bounds__(256) void gemm1_k(const float* __restrict__ x,
                                               const float* __restrict__ W1,
                                               float* __restrict__ part) {
  __shared__ float As[BK * LDA];  // [k][m]
  __shared__ float Bs[BK * F1];   // [k][n]
  int tid = threadIdx.x;
  int m0 = blockIdx.x * BM;
  int kbase = blockIdx.y * 4096;

  int arow = tid >> 4;   // 0..15
  int acol4 = tid & 15;  // 0..15
  int tm = tid & 7;      // 8 m-groups of 4
  int tn = tid >> 3;     // 32 n-groups of 4

  float acc[4][4];
#pragma unroll
  for (int i = 0; i < 4; i++)
#pragma unroll
    for (int j = 0; j < 4; j++) acc[i][j] = 0.f;

  for (int kt = 0; kt < 64; ++kt) {
    int k0 = kbase + kt * BK;
    float4 a0 = *(const float4*)&x[(size_t)(m0 + arow) * N_NODES + k0 + 4 * acol4];
    float4 a1 = *(const float4*)&x[(size_t)(m0 + arow + 16) * N_NODES + k0 + 4 * acol4];
    float4 b[8];
#pragma unroll
    for (int j = 0; j < 8; j++) {
      int idx = tid + 256 * j;  // 0..2047
      int br = idx >> 5;        // 0..63
      int bc4 = idx & 31;       // 0..31
      b[j] = *(const float4*)&W1[(size_t)(k0 + br) * F1 + 4 * bc4];
    }
    __syncthreads();
    As[(4 * acol4 + 0) * LDA + arow] = a0.x;
    As[(4 * acol4 + 1) * LDA + arow] = a0.y;
    As[(4 * acol4 + 2) * LDA + arow] = a0.z;
    As[(4 * acol4 + 3) * LDA + arow] = a0.w;
    As[(4 * acol4 + 0) * LDA + arow + 16] = a1.x;
    As[(4 * acol4 + 1) * LDA + arow + 16] = a1.y;
    As[(4 * acol4 + 2) * LDA + arow + 16] = a1.z;
    As[(4 * acol4 + 3) * LDA + arow + 16] = a1.w;
#pragma unroll
    for (int j = 0; j < 8; j++) {
      int idx = tid + 256 * j;
      *(float4*)&Bs[idx * 4] = b[j];
    }
    __syncthreads();
#pragma unroll 16
    for (int kk = 0; kk < BK; ++kk) {
      float4 av = *(float4*)&As[kk * LDA + 4 * tm];
      float4 bv = *(float4*)&Bs[kk * F1 + 4 * tn];
      acc[0][0] += av.x * bv.x; acc[0][1] += av.x * bv.y; acc[0][2] += av.x * bv.z; acc[0][3] += av.x * bv.w;
      acc[1][0] += av.y * bv.x; acc[1][1] += av.y * bv.y; acc[1][2] += av.y * bv.z; acc[1][3] += av.y * bv.w;
      acc[2][0] += av.z * bv.x; acc[2][1] += av.z * bv.y; acc[2][2] += av.z * bv.z; acc[2][3] += av.z * bv.w;
      acc[3][0] += av.w * bv.x; acc[3][1] += av.w * bv.y; acc[3][2] += av.w * bv.z; acc[3][3] += av.w * bv.w;
    }
  }
  float* outp = part + (size_t)blockIdx.y * N_NODES * F1;
#pragma unroll
  for (int i = 0; i < 4; i++) {
    int row = m0 + 4 * tm + i;
    float4 o = make_float4(acc[i][0], acc[i][1], acc[i][2], acc[i][3]);
    *(float4*)&outp[(size_t)row * F1 + 4 * tn] = o;
  }
}

// in-place safe: each thread reads part[i] and part[i + NF] fully before
// writing xw1[i] where xw1 aliases part (index-aligned).
__global__ void reduce_k(const float* __restrict__ part, float* __restrict__ xw1) {
  int i = blockIdx.x * blockDim.x + threadIdx.x;  // float4 index, 262144 total
  float4 a = ((const float4*)part)[i];
  float4 b = ((const float4*)(part + (size_t)N_NODES * F1))[i];
  float4 o = make_float4(a.x + b.x, a.y + b.y, a.z + b.z, a.w + b.w);
  ((float4*)xw1)[i] = o;
}

// ---------------- aggregation (gather over CSR) + bias + relu ----------------

template <int F>
__global__ void agg_k(const float* __restrict__ xw, const int* __restrict__ csr,
                      const int* __restrict__ rp, const float* __restrict__ dinv,
                      const float* __restrict__ bias, float* __restrict__ hout) {
  int node = blockIdx.x;
  int f = threadIdx.x;  // F threads
  __shared__ int sidx[F];
  __shared__ float sdv[F];
  int beg = rp[node], end = rp[node + 1];
  float acc = 0.f;
  for (int base = beg; base < end; base += F) {
    int n = end - base;
    if (n > F) n = F;
    __syncthreads();
    if (f < n) {
      int s = csr[base + f];
      sidx[f] = s;
      sdv[f] = dinv[s];
    }
    __syncthreads();
    for (int i = 0; i < n; i++) acc += xw[(size_t)sidx[i] * F + f] * sdv[i];
  }
  float dv = dinv[node];
  float v = (acc + xw[(size_t)node * F + f] * dv) * dv + bias[f];
  hout[(size_t)node * F + f] = v > 0.f ? v : 0.f;
}

// ---------------- GEMM2: h1[8192,128] @ W2[128,64] ----------------

__global__ __launch_bounds__(256) void gemm2_k(const float* __restrict__ h1,
                                               const float* __restrict__ W2,
                                               float* __restrict__ xw2) {
  __shared__ float W2s[F1 * F2];  // 32KB
  __shared__ float As[16 * F1];   // 8KB
  int tid = threadIdx.x;
  int r0 = blockIdx.x * 16;
#pragma unroll
  for (int j = 0; j < 8; j++)
    ((float4*)W2s)[tid + 256 * j] = ((const float4*)W2)[tid + 256 * j];
#pragma unroll
  for (int j = 0; j < 2; j++)
    ((float4*)As)[tid + 256 * j] = ((const float4*)(h1 + (size_t)r0 * F1))[tid + 256 * j];
  __syncthreads();
  int r = tid >> 4, c4 = tid & 15;
  float4 acc = make_float4(0.f, 0.f, 0.f, 0.f);
#pragma unroll 8
  for (int k = 0; k < F1; k++) {
    float a = As[r * F1 + k];
    float4 bv = *(float4*)&W2s[k * F2 + 4 * c4];
    acc.x += a * bv.x; acc.y += a * bv.y; acc.z += a * bv.z; acc.w += a * bv.w;
  }
  *(float4*)&xw2[(size_t)(r0 + r) * F2 + 4 * c4] = acc;
}

// ---------------- P tables: P[i][0:86]=h2[i]@Wfc[:64], P[i][86:172]=h2[i]@Wfc[64:] ----------------

__global__ void pboth_k(const float* __restrict__ h2, const float* __restrict__ Wfc,
                        float* __restrict__ P) {
  __shared__ float hs[64 * 16];  // [k][r]
  int tid = threadIdx.x;         // 192
  int r0 = blockIdx.x * 16;
  for (int idx = tid; idx < 256; idx += 192) {
    int row = idx >> 4, k4 = idx & 15;
    float4 h = *(const float4*)&h2[(size_t)(r0 + row) * F2 + 4 * k4];
    hs[(4 * k4 + 0) * 16 + row] = h.x;
    hs[(4 * k4 + 1) * 16 + row] = h.y;
    hs[(4 * k4 + 2) * 16 + row] = h.z;
    hs[(4 * k4 + 3) * 16 + row] = h.w;
  }
  __syncthreads();
  if (tid < 172) {
    int half = tid < 86 ? 0 : 1;
    int j = tid - 86 * half;
    const float* wp = Wfc + (size_t)(64 * half) * N_TYPES + j;
    float acc[16];
#pragma unroll
    for (int r = 0; r < 16; r++) acc[r] = 0.f;
    for (int k = 0; k < 64; k++) {
      float w = wp[(size_t)k * N_TYPES];
      const float* hk = &hs[k * 16];
#pragma unroll
      for (int r = 0; r < 16; r++) acc[r] += hk[r] * w;
    }
#pragma unroll
    for (int r = 0; r < 16; r++) P[(size_t)(r0 + r) * 172 + tid] = acc[r];
  }
}

// ---------------- final: out[p][t] = sigmoid(P1[d1[p]][t] + P2[d2[p]][t] + bfc[t]) ----------------

__global__ void final_k(const float* __restrict__ P, const int* __restrict__ d1,
                        const int* __restrict__ d2, const float* __restrict__ bfc,
                        float* __restrict__ out) {
  int gid = blockIdx.x * blockDim.x + threadIdx.x;
  if (gid >= N_PAIRS * 43) return;
  int p = gid / 43;
  int j = gid - p * 43;
  int a = d1[p], b = d2[p];
  float2 v1 = *(const float2*)&P[(size_t)a * 172 + 2 * j];
  float2 v2 = *(const float2*)&P[(size_t)b * 172 + 86 + 2 * j];
  float2 bb = *(const float2*)&bfc[2 * j];
  float z0 = v1.x + v2.x + bb.x;
  float z1 = v1.y + v2.y + bb.y;
  float2 o;
  o.x = 1.0f / (1.0f + expf(-z0));
  o.y = 1.0f / (1.0f + expf(-z1));
  *(float2*)&out[(size_t)p * 86 + 2 * j] = o;
}

// ---------------- launch ----------------

extern "C" void kernel_launch(void* const* d_in, const int* in_sizes, int n_in,
                              void* d_out, int out_size, void* d_ws, size_t ws_size,
                              hipStream_t stream) {
  const float* x   = (const float*)d_in[0];
  const int*   ei  = (const int*)d_in[1];
  const int*   d1  = (const int*)d_in[2];
  const int*   d2  = (const int*)d_in[3];
  const float* W1  = (const float*)d_in[4];
  const float* b1  = (const float*)d_in[5];
  const float* W2  = (const float*)d_in[6];
  const float* b2  = (const float*)d_in[7];
  const float* Wfc = (const float*)d_in[8];
  const float* bfc = (const float*)d_in[9];
  float* out = (float*)d_out;

  const int* esrc = ei;
  const int* edst = ei + N_EDGES;

  char* w = (char*)d_ws;
  size_t off = 0;
  auto alloc = [&](size_t bytes) -> char* {
    char* p = w + off;
    off += (bytes + 255) & ~(size_t)255;
    return p;
  };
  int*   cnt  = (int*)alloc((size_t)N_NODES * 4);
  float* dinv = (float*)alloc((size_t)N_NODES * 4);
  int*   rp   = (int*)alloc((size_t)(N_NODES + 1) * 4);
  int*   fill = (int*)alloc((size_t)N_NODES * 4);
  int*   csr  = (int*)alloc((size_t)N_EDGES * 4);
  float* part = (float*)alloc(2ull * N_NODES * F1 * 4);  // xw1 aliases part[0]
  float* h1   = (float*)alloc((size_t)N_NODES * F1 * 4);
  float* xw2  = (float*)alloc((size_t)N_NODES * F2 * 4);
  float* h2   = (float*)alloc((size_t)N_NODES * F2 * 4);
  float* P    = (float*)alloc((size_t)N_NODES * 172 * 4);
  float* xw1  = part;  // alias: reduce_k is index-aligned in-place safe
  if (off > ws_size) return;  // ~25MB needed

  hipMemsetAsync(cnt, 0, (size_t)N_NODES * 4, stream);
  count_deg_k<<<N_EDGES / 256, 256, 0, stream>>>(edst, cnt);
  dinv_k<<<N_NODES / 256, 256, 0, stream>>>(cnt, dinv);
  scan_k<<<1, 1024, 0, stream>>>(cnt, rp, fill);
  scatter_k<<<N_EDGES / 256, 256, 0, stream>>>(esrc, edst, fill, csr);

  gemm1_k<<<dim3(N_NODES / BM, 2), 256, 0, stream>>>(x, W1, part);
  reduce_k<<<(N_NODES * F1 / 4) / 256, 256, 0, stream>>>(part, xw1);
  agg_k<F1><<<N_NODES, F1, 0, stream>>>(xw1, csr, rp, dinv, b1, h1);

  gemm2_k<<<N_NODES / 16, 256, 0, stream>>>(h1, W2, xw2);
  agg_k<F2><<<N_NODES, F2, 0, stream>>>(xw2, csr, rp, dinv, b2, h2);

  pboth_k<<<N_NODES / 16, 192, 0, stream>>>(h2, Wfc, P);
  final_k<<<(N_PAIRS * 43) / 256, 256, 0, stream>>>(P, d1, d2, bfc, out);
}

// Round 3
// 491.425 us; speedup vs baseline: 1.2454x; 1.2454x over previous
//
#include <hip/hip_runtime.h>
#include <math.h>
#include <stdint.h>
#include <stddef.h>

#define N_NODES 8192
#define N_EDGES 524288
#define N_PAIRS 262144
#define N_TYPES 86
#define F1 128
#define F2 64

typedef unsigned short ushort_t;
typedef unsigned int uint_t;
typedef __attribute__((ext_vector_type(8))) short bfrag;
typedef __attribute__((ext_vector_type(4))) float ffrag;

__device__ inline ushort_t f2bf(float f) {
  uint_t u = __float_as_uint(f);
  uint_t r = u + 0x7fffu + ((u >> 16) & 1u);
  return (ushort_t)(r >> 16);
}
__device__ inline float bf2f(ushort_t h) {
  return __uint_as_float(((uint_t)h) << 16);
}

// ---------------- degree / CSR build ----------------

__global__ void count_deg_k(const int* __restrict__ dst, int* __restrict__ cnt) {
  int e = blockIdx.x * blockDim.x + threadIdx.x;
  if (e < N_EDGES) atomicAdd(&cnt[dst[e]], 1);
}

__global__ void dinv_k(const int* __restrict__ cnt, float* __restrict__ dinv) {
  int i = blockIdx.x * blockDim.x + threadIdx.x;
  if (i < N_NODES) dinv[i] = 1.0f / sqrtf((float)(cnt[i] + 1)); // +1 self-loop
}

__global__ void scan_k(const int* __restrict__ cnt, int* __restrict__ rp,
                       int* __restrict__ fill) {
  __shared__ int s[1024];
  int t = threadIdx.x;
  int v[8];
  int sum = 0;
#pragma unroll
  for (int i = 0; i < 8; i++) { v[i] = cnt[t * 8 + i]; sum += v[i]; }
  s[t] = sum;
  __syncthreads();
  for (int off = 1; off < 1024; off <<= 1) {
    int add = (t >= off) ? s[t - off] : 0;
    __syncthreads();
    s[t] += add;
    __syncthreads();
  }
  int excl = s[t] - sum;
#pragma unroll
  for (int i = 0; i < 8; i++) {
    rp[t * 8 + i] = excl;
    fill[t * 8 + i] = excl;
    excl += v[i];
  }
  if (t == 1023) rp[N_NODES] = excl;
}

__global__ void scatter_k(const int* __restrict__ src, const int* __restrict__ dst,
                          int* fill, int* __restrict__ csr) {
  int e = blockIdx.x * blockDim.x + threadIdx.x;
  if (e < N_EDGES) {
    int d = dst[e];
    int pos = atomicAdd(&fill[d], 1);
    csr[pos] = src[e];
  }
}

// ---------------- W1 split + transpose: W1th/W1tl[n][k] = hi/lo(W1[k][n]) ----------------

__global__ __launch_bounds__(256) void w1split_k(const float* __restrict__ W1,
                                                 ushort_t* __restrict__ W1th,
                                                 ushort_t* __restrict__ W1tl) {
  __shared__ ushort_t lh[32 * 65];
  __shared__ ushort_t ll[32 * 65];
  int tid = threadIdx.x;
  int k0 = blockIdx.x * 64;  // 128 blocks over K
  int n0 = blockIdx.y * 32;  // 4 blocks over N
#pragma unroll
  for (int i = 0; i < 8; i++) {
    int c = tid + 256 * i;  // 0..2047
    int kr = c >> 5, nc = c & 31;
    float v = W1[(size_t)(k0 + kr) * F1 + n0 + nc];
    ushort_t h = f2bf(v);
    ushort_t l = f2bf(v - bf2f(h));
    lh[nc * 65 + kr] = h;
    ll[nc * 65 + kr] = l;
  }
  __syncthreads();
#pragma unroll
  for (int i = 0; i < 2; i++) {
    int c = tid + 256 * i;  // 0..511
    int buf = c >> 8;
    int cc = c & 255;
    int nr = cc >> 3, kc = cc & 7;
    const ushort_t* l = buf ? ll : lh;
    uint4 u;
    uint_t w0 = (uint_t)l[nr * 65 + kc * 8 + 0] | ((uint_t)l[nr * 65 + kc * 8 + 1] << 16);
    uint_t w1 = (uint_t)l[nr * 65 + kc * 8 + 2] | ((uint_t)l[nr * 65 + kc * 8 + 3] << 16);
    uint_t w2 = (uint_t)l[nr * 65 + kc * 8 + 4] | ((uint_t)l[nr * 65 + kc * 8 + 5] << 16);
    uint_t w3 = (uint_t)l[nr * 65 + kc * 8 + 6] | ((uint_t)l[nr * 65 + kc * 8 + 7] << 16);
    u.x = w0; u.y = w1; u.z = w2; u.w = w3;
    ushort_t* dst = (buf ? W1tl : W1th) + (size_t)(n0 + nr) * N_NODES + k0 + kc * 8;
    *(uint4*)dst = u;
  }
}

// ---------------- GEMM1 (MFMA, split-bf16 3-term): x[8192,8192] @ W1[8192,128] ----------------
// tile: BM=64, BN=128(all), BK=64; 4 waves; K-split grid.y = S
// LDS: Ah[64][64]bf16(8K) Al(8K) Bh[128][64]bf16(16K) Bl(16K) = 48KB, XOR-swizzled

#define LDSA_H 0
#define LDSA_L 8192
#define LDSB_H 16384
#define LDSB_L 32768

__global__ __launch_bounds__(256) void gemm1_mfma_k(const float* __restrict__ x,
                                                    const ushort_t* __restrict__ W1th,
                                                    const ushort_t* __restrict__ W1tl,
                                                    float* __restrict__ part, int kspan) {
  __shared__ __align__(16) char lds[49152];
  int tid = threadIdx.x;
  int m_blk = blockIdx.x * 64;
  int kbase = blockIdx.y * kspan;
  int ktiles = kspan >> 6;
  int wave = tid >> 6, lane = tid & 63;
  int lrow = lane & 15, kgrp = lane >> 4;
  int xr = (lrow & 7) << 4;
  int kb0 = kgrp * 16;

  ffrag acc[4][2];
#pragma unroll
  for (int mi = 0; mi < 4; mi++)
#pragma unroll
    for (int ni = 0; ni < 2; ni++) acc[mi][ni] = (ffrag)(0.0f);

  for (int kt = 0; kt < ktiles; ++kt) {
    int k0 = kbase + (kt << 6);
    // -------- global loads (regs) --------
    float4 av[4];
#pragma unroll
    for (int i = 0; i < 4; i++) {
      int c = tid + 256 * i;  // 0..1023
      int row = c >> 4, c4 = c & 15;
      av[i] = *(const float4*)&x[(size_t)(m_blk + row) * N_NODES + k0 + c4 * 4];
    }
    uint4 bv[8];
#pragma unroll
    for (int i = 0; i < 8; i++) {
      int c = tid + 256 * i;  // 0..2047
      const ushort_t* src = (i < 4) ? W1th : W1tl;
      int cc = c & 1023;
      int row = cc >> 3, kc = cc & 7;
      bv[i] = *(const uint4*)&src[(size_t)row * N_NODES + k0 + kc * 8];
    }
    __syncthreads();
    // -------- LDS writes (swizzled) --------
#pragma unroll
    for (int i = 0; i < 4; i++) {
      int c = tid + 256 * i;
      int row = c >> 4, c4 = c & 15;
      float fx0 = av[i].x, fx1 = av[i].y, fx2 = av[i].z, fx3 = av[i].w;
      ushort_t h0 = f2bf(fx0), h1 = f2bf(fx1), h2 = f2bf(fx2), h3 = f2bf(fx3);
      ushort_t l0 = f2bf(fx0 - bf2f(h0)), l1 = f2bf(fx1 - bf2f(h1));
      ushort_t l2 = f2bf(fx2 - bf2f(h2)), l3 = f2bf(fx3 - bf2f(h3));
      uint2 hp, lp;
      hp.x = (uint_t)h0 | ((uint_t)h1 << 16); hp.y = (uint_t)h2 | ((uint_t)h3 << 16);
      lp.x = (uint_t)l0 | ((uint_t)l1 << 16); lp.y = (uint_t)l2 | ((uint_t)l3 << 16);
      uint_t off = row * 128 + ((c4 * 8) ^ ((row & 7) << 4));
      *(uint2*)(lds + LDSA_H + off) = hp;
      *(uint2*)(lds + LDSA_L + off) = lp;
    }
#pragma unroll
    for (int i = 0; i < 8; i++) {
      int c = tid + 256 * i;
      int base = (i < 4) ? LDSB_H : LDSB_L;
      int cc = c & 1023;
      int row = cc >> 3, kc = cc & 7;
      uint_t off = row * 128 + ((kc * 16) ^ ((row & 7) << 4));
      *(uint4*)(lds + base + off) = bv[i];
    }
    __syncthreads();
    // -------- MFMA --------
#pragma unroll
    for (int ks = 0; ks < 2; ++ks) {
      int cb = ks * 64 + kb0;
      bfrag bh[2], bl[2];
#pragma unroll
      for (int ni = 0; ni < 2; ni++) {
        int brow = wave * 32 + ni * 16 + lrow;
        uint_t boff = brow * 128 + (cb ^ xr);
        bh[ni] = *(const bfrag*)(lds + LDSB_H + boff);
        bl[ni] = *(const bfrag*)(lds + LDSB_L + boff);
      }
#pragma unroll
      for (int mi = 0; mi < 4; mi++) {
        int arow = mi * 16 + lrow;
        uint_t aoff = arow * 128 + (cb ^ xr);
        bfrag ah = *(const bfrag*)(lds + LDSA_H + aoff);
        bfrag al = *(const bfrag*)(lds + LDSA_L + aoff);
#pragma unroll
        for (int ni = 0; ni < 2; ni++) {
          acc[mi][ni] = __builtin_amdgcn_mfma_f32_16x16x32_bf16(ah, bh[ni], acc[mi][ni], 0, 0, 0);
          acc[mi][ni] = __builtin_amdgcn_mfma_f32_16x16x32_bf16(ah, bl[ni], acc[mi][ni], 0, 0, 0);
          acc[mi][ni] = __builtin_amdgcn_mfma_f32_16x16x32_bf16(al, bh[ni], acc[mi][ni], 0, 0, 0);
        }
      }
    }
  }
  // -------- epilogue: C[row=(lane>>4)*4+r][col=lane&15] per 16x16 frag --------
  float* outp = part + (size_t)blockIdx.y * (N_NODES * F1);
#pragma unroll
  for (int mi = 0; mi < 4; mi++) {
#pragma unroll
    for (int ni = 0; ni < 2; ni++) {
      int col = wave * 32 + ni * 16 + lrow;
#pragma unroll
      for (int r = 0; r < 4; r++) {
        int row = m_blk + mi * 16 + kgrp * 4 + r;
        outp[(size_t)row * F1 + col] = acc[mi][ni][r];
      }
    }
  }
}

// in-place safe: each thread reads all S parts at its index, then writes part[0].
__global__ void reduceS_k(const float* __restrict__ part, float* __restrict__ xw1, int S) {
  int i = blockIdx.x * blockDim.x + threadIdx.x;  // float4 index
  float4 a = ((const float4*)part)[i];
  for (int s = 1; s < S; s++) {
    float4 b = ((const float4*)(part + (size_t)s * N_NODES * F1))[i];
    a.x += b.x; a.y += b.y; a.z += b.z; a.w += b.w;
  }
  ((float4*)xw1)[i] = a;
}

// ---------------- aggregation (gather over CSR) + bias + relu ----------------

template <int F>
__global__ void agg_k(const float* __restrict__ xw, const int* __restrict__ csr,
                      const int* __restrict__ rp, const float* __restrict__ dinv,
                      const float* __restrict__ bias, float* __restrict__ hout) {
  int node = blockIdx.x;
  int f = threadIdx.x;  // F threads
  __shared__ int sidx[F];
  __shared__ float sdv[F];
  int beg = rp[node], end = rp[node + 1];
  float acc = 0.f;
  for (int base = beg; base < end; base += F) {
    int n = end - base;
    if (n > F) n = F;
    __syncthreads();
    if (f < n) {
      int s = csr[base + f];
      sidx[f] = s;
      sdv[f] = dinv[s];
    }
    __syncthreads();
    for (int i = 0; i < n; i++) acc += xw[(size_t)sidx[i] * F + f] * sdv[i];
  }
  float dv = dinv[node];
  float v = (acc + xw[(size_t)node * F + f] * dv) * dv + bias[f];
  hout[(size_t)node * F + f] = v > 0.f ? v : 0.f;
}

// ---------------- GEMM2: h1[8192,128] @ W2[128,64] ----------------

__global__ __launch_bounds__(256) void gemm2_k(const float* __restrict__ h1,
                                               const float* __restrict__ W2,
                                               float* __restrict__ xw2) {
  __shared__ float W2s[F1 * F2];
  __shared__ float As[16 * F1];
  int tid = threadIdx.x;
  int r0 = blockIdx.x * 16;
#pragma unroll
  for (int j = 0; j < 8; j++)
    ((float4*)W2s)[tid + 256 * j] = ((const float4*)W2)[tid + 256 * j];
#pragma unroll
  for (int j = 0; j < 2; j++)
    ((float4*)As)[tid + 256 * j] = ((const float4*)(h1 + (size_t)r0 * F1))[tid + 256 * j];
  __syncthreads();
  int r = tid >> 4, c4 = tid & 15;
  float4 acc = make_float4(0.f, 0.f, 0.f, 0.f);
#pragma unroll 8
  for (int k = 0; k < F1; k++) {
    float a = As[r * F1 + k];
    float4 bv = *(float4*)&W2s[k * F2 + 4 * c4];
    acc.x += a * bv.x; acc.y += a * bv.y; acc.z += a * bv.z; acc.w += a * bv.w;
  }
  *(float4*)&xw2[(size_t)(r0 + r) * F2 + 4 * c4] = acc;
}

// ---------------- P tables: P[i][0:86]=h2[i]@Wfc[:64], P[i][86:172]=h2[i]@Wfc[64:] ----------------

__global__ void pboth_k(const float* __restrict__ h2, const float* __restrict__ Wfc,
                        float* __restrict__ P) {
  __shared__ float hs[64 * 16];  // [k][r]
  int tid = threadIdx.x;         // 192
  int r0 = blockIdx.x * 16;
  for (int idx = tid; idx < 256; idx += 192) {
    int row = idx >> 4, k4 = idx & 15;
    float4 h = *(const float4*)&h2[(size_t)(r0 + row) * F2 + 4 * k4];
    hs[(4 * k4 + 0) * 16 + row] = h.x;
    hs[(4 * k4 + 1) * 16 + row] = h.y;
    hs[(4 * k4 + 2) * 16 + row] = h.z;
    hs[(4 * k4 + 3) * 16 + row] = h.w;
  }
  __syncthreads();
  if (tid < 172) {
    int half = tid < 86 ? 0 : 1;
    int j = tid - 86 * half;
    const float* wp = Wfc + (size_t)(64 * half) * N_TYPES + j;
    float acc[16];
#pragma unroll
    for (int r = 0; r < 16; r++) acc[r] = 0.f;
    for (int k = 0; k < 64; k++) {
      float w = wp[(size_t)k * N_TYPES];
      const float* hk = &hs[k * 16];
#pragma unroll
      for (int r = 0; r < 16; r++) acc[r] += hk[r] * w;
    }
#pragma unroll
    for (int r = 0; r < 16; r++) P[(size_t)(r0 + r) * 172 + tid] = acc[r];
  }
}

// ---------------- final: out[p][t] = sigmoid(P1[d1[p]][t] + P2[d2[p]][t] + bfc[t]) ----------------

__global__ void final_k(const float* __restrict__ P, const int* __restrict__ d1,
                        const int* __restrict__ d2, const float* __restrict__ bfc,
                        float* __restrict__ out) {
  int gid = blockIdx.x * blockDim.x + threadIdx.x;
  if (gid >= N_PAIRS * 43) return;
  int p = gid / 43;
  int j = gid - p * 43;
  int a = d1[p], b = d2[p];
  float2 v1 = *(const float2*)&P[(size_t)a * 172 + 2 * j];
  float2 v2 = *(const float2*)&P[(size_t)b * 172 + 86 + 2 * j];
  float2 bb = *(const float2*)&bfc[2 * j];
  float z0 = v1.x + v2.x + bb.x;
  float z1 = v1.y + v2.y + bb.y;
  float2 o;
  o.x = 1.0f / (1.0f + expf(-z0));
  o.y = 1.0f / (1.0f + expf(-z1));
  *(float2*)&out[(size_t)p * 86 + 2 * j] = o;
}

// ---------------- launch ----------------

extern "C" void kernel_launch(void* const* d_in, const int* in_sizes, int n_in,
                              void* d_out, int out_size, void* d_ws, size_t ws_size,
                              hipStream_t stream) {
  const float* x   = (const float*)d_in[0];
  const int*   ei  = (const int*)d_in[1];
  const int*   d1  = (const int*)d_in[2];
  const int*   d2  = (const int*)d_in[3];
  const float* W1  = (const float*)d_in[4];
  const float* b1  = (const float*)d_in[5];
  const float* W2  = (const float*)d_in[6];
  const float* b2  = (const float*)d_in[7];
  const float* Wfc = (const float*)d_in[8];
  const float* bfc = (const float*)d_in[9];
  float* out = (float*)d_out;

  const int* esrc = ei;
  const int* edst = ei + N_EDGES;

  char* w = (char*)d_ws;
  size_t off = 0;
  auto alloc = [&](size_t bytes) -> char* {
    char* p = w + off;
    off += (bytes + 255) & ~(size_t)255;
    return p;
  };
  int*      cnt  = (int*)alloc((size_t)N_NODES * 4);
  float*    dinv = (float*)alloc((size_t)N_NODES * 4);
  int*      rp   = (int*)alloc((size_t)(N_NODES + 1) * 4);
  int*      fill = (int*)alloc((size_t)N_NODES * 4);
  int*      csr  = (int*)alloc((size_t)N_EDGES * 4);
  ushort_t* W1th = (ushort_t*)alloc((size_t)N_NODES * F1 * 2);
  ushort_t* W1tl = (ushort_t*)alloc((size_t)N_NODES * F1 * 2);
  float*    h1   = (float*)alloc((size_t)N_NODES * F1 * 4);
  float*    xw2  = (float*)alloc((size_t)N_NODES * F2 * 4);
  float*    h2   = (float*)alloc((size_t)N_NODES * F2 * 4);
  float*    P    = (float*)alloc((size_t)N_NODES * 172 * 4);

  // K-split factor chosen from remaining workspace (deterministic: ws fixed)
  size_t partBytes = (size_t)N_NODES * F1 * 4;  // 4MB per split
  int S = 8;
  while (S > 1 && off + (size_t)S * partBytes > ws_size) S >>= 1;
  float* part = (float*)alloc((size_t)S * partBytes);
  float* xw1 = part;  // alias; reduceS_k is index-aligned in-place safe
  if (off > ws_size) return;

  hipMemsetAsync(cnt, 0, (size_t)N_NODES * 4, stream);
  count_deg_k<<<N_EDGES / 256, 256, 0, stream>>>(edst, cnt);
  dinv_k<<<N_NODES / 256, 256, 0, stream>>>(cnt, dinv);
  scan_k<<<1, 1024, 0, stream>>>(cnt, rp, fill);
  scatter_k<<<N_EDGES / 256, 256, 0, stream>>>(esrc, edst, fill, csr);

  w1split_k<<<dim3(N_NODES / 64, F1 / 32), 256, 0, stream>>>(W1, W1th, W1tl);
  gemm1_mfma_k<<<dim3(N_NODES / 64, S), 256, 0, stream>>>(x, W1th, W1tl, part, N_NODES / S);
  if (S > 1)
    reduceS_k<<<(N_NODES * F1 / 4) / 256, 256, 0, stream>>>(part, xw1, S);
  agg_k<F1><<<N_NODES, F1, 0, stream>>>(xw1, csr, rp, dinv, b1, h1);

  gemm2_k<<<N_NODES / 16, 256, 0, stream>>>(h1, W2, xw2);
  agg_k<F2><<<N_NODES, F2, 0, stream>>>(xw2, csr, rp, dinv, b2, h2);

  pboth_k<<<N_NODES / 16, 192, 0, stream>>>(h2, Wfc, P);
  final_k<<<(N_PAIRS * 43) / 256, 256, 0, stream>>>(P, d1, d2, bfc, out);
}

// Round 4
// 346.590 us; speedup vs baseline: 1.7658x; 1.4179x over previous
//
#include <hip/hip_runtime.h>
#include <math.h>
#include <stdint.h>
#include <stddef.h>

#define N_NODES 8192
#define N_EDGES 524288
#define N_PAIRS 262144
#define N_TYPES 86
#define F1 128
#define F2 64

typedef unsigned short ushort_t;
typedef unsigned int uint_t;
typedef __attribute__((ext_vector_type(8))) short bfrag;
typedef __attribute__((ext_vector_type(4))) float ffrag;

__device__ inline ushort_t f2bf(float f) {
  uint_t u = __float_as_uint(f);
  uint_t r = u + 0x7fffu + ((u >> 16) & 1u);
  return (ushort_t)(r >> 16);
}
__device__ inline float bf2f(ushort_t h) {
  return __uint_as_float(((uint_t)h) << 16);
}

// ---------------- degree / CSR build ----------------

__global__ void count_deg_k(const int* __restrict__ dst, int* __restrict__ cnt) {
  int e = blockIdx.x * blockDim.x + threadIdx.x;
  if (e < N_EDGES) atomicAdd(&cnt[dst[e]], 1);
}

__global__ void dinv_k(const int* __restrict__ cnt, float* __restrict__ dinv) {
  int i = blockIdx.x * blockDim.x + threadIdx.x;
  if (i < N_NODES) dinv[i] = 1.0f / sqrtf((float)(cnt[i] + 1)); // +1 self-loop
}

__global__ void scan_k(const int* __restrict__ cnt, int* __restrict__ rp,
                       int* __restrict__ fill) {
  __shared__ int s[1024];
  int t = threadIdx.x;
  int v[8];
  int sum = 0;
#pragma unroll
  for (int i = 0; i < 8; i++) { v[i] = cnt[t * 8 + i]; sum += v[i]; }
  s[t] = sum;
  __syncthreads();
  for (int off = 1; off < 1024; off <<= 1) {
    int add = (t >= off) ? s[t - off] : 0;
    __syncthreads();
    s[t] += add;
    __syncthreads();
  }
  int excl = s[t] - sum;
#pragma unroll
  for (int i = 0; i < 8; i++) {
    rp[t * 8 + i] = excl;
    fill[t * 8 + i] = excl;
    excl += v[i];
  }
  if (t == 1023) rp[N_NODES] = excl;
}

__global__ void scatter_k(const int* __restrict__ src, const int* __restrict__ dst,
                          int* fill, int* __restrict__ csr) {
  int e = blockIdx.x * blockDim.x + threadIdx.x;
  if (e < N_EDGES) {
    int d = dst[e];
    int pos = atomicAdd(&fill[d], 1);
    csr[pos] = src[e];
  }
}

// ---------------- W1 split + transpose: W1th/W1tl[n][k] = hi/lo(W1[k][n]) ----------------

__global__ __launch_bounds__(256) void w1split_k(const float* __restrict__ W1,
                                                 ushort_t* __restrict__ W1th,
                                                 ushort_t* __restrict__ W1tl) {
  __shared__ ushort_t lh[32 * 65];
  __shared__ ushort_t ll[32 * 65];
  int tid = threadIdx.x;
  int k0 = blockIdx.x * 64;
  int n0 = blockIdx.y * 32;
#pragma unroll
  for (int i = 0; i < 8; i++) {
    int c = tid + 256 * i;
    int kr = c >> 5, nc = c & 31;
    float v = W1[(size_t)(k0 + kr) * F1 + n0 + nc];
    ushort_t h = f2bf(v);
    ushort_t l = f2bf(v - bf2f(h));
    lh[nc * 65 + kr] = h;
    ll[nc * 65 + kr] = l;
  }
  __syncthreads();
#pragma unroll
  for (int i = 0; i < 2; i++) {
    int c = tid + 256 * i;
    int buf = c >> 8;
    int cc = c & 255;
    int nr = cc >> 3, kc = cc & 7;
    const ushort_t* l = buf ? ll : lh;
    uint4 u;
    u.x = (uint_t)l[nr * 65 + kc * 8 + 0] | ((uint_t)l[nr * 65 + kc * 8 + 1] << 16);
    u.y = (uint_t)l[nr * 65 + kc * 8 + 2] | ((uint_t)l[nr * 65 + kc * 8 + 3] << 16);
    u.z = (uint_t)l[nr * 65 + kc * 8 + 4] | ((uint_t)l[nr * 65 + kc * 8 + 5] << 16);
    u.w = (uint_t)l[nr * 65 + kc * 8 + 6] | ((uint_t)l[nr * 65 + kc * 8 + 7] << 16);
    ushort_t* dst = (buf ? W1tl : W1th) + (size_t)(n0 + nr) * N_NODES + k0 + kc * 8;
    *(uint4*)dst = u;
  }
}

// ---------------- GEMM1 (MFMA, split-bf16 3-term, T14 pipelined) ----------------
// tile: BM=128, BN=128(all), BK=64; 4 waves (2x2); K-split grid.y = S
// LDS: Ah 16K | Al 16K | Bh 16K | Bl 16K = 64KB, XOR-swizzled rows (128B)

#define LDSA_H 0
#define LDSA_L 16384
#define LDSB_H 32768
#define LDSB_L 49152

__global__ __launch_bounds__(256) void gemm1_mfma_k(const float* __restrict__ x,
                                                    const ushort_t* __restrict__ W1th,
                                                    const ushort_t* __restrict__ W1tl,
                                                    float* __restrict__ part, int kspan) {
  __shared__ __align__(16) char lds[65536];
  int tid = threadIdx.x;
  int m_blk = blockIdx.x * 128;
  int kbase = blockIdx.y * kspan;
  int ktiles = kspan >> 6;
  int wave = tid >> 6, lane = tid & 63;
  int wr = wave >> 1, wc = wave & 1;
  int lrow = lane & 15, kgrp = lane >> 4;
  int xr = (lrow & 7) << 4;
  int kb0 = kgrp * 16;

  ffrag acc[4][4];
#pragma unroll
  for (int mi = 0; mi < 4; mi++)
#pragma unroll
    for (int ni = 0; ni < 4; ni++) acc[mi][ni] = (ffrag)(0.0f);

  // staging registers (second buffer of the pipeline)
  float4 av[8];
  uint4 bv[8];

  // precomputed per-thread staging coordinates
  int a_row = 0, a_c4 = 0;   // pattern: c = tid + 256*i -> row = c>>4, c4 = c&15
  (void)a_row; (void)a_c4;

#define LOAD_TILE(KT)                                                              \
  {                                                                                \
    int k0_ = kbase + ((KT) << 6);                                                 \
    _Pragma("unroll") for (int i = 0; i < 8; i++) {                                \
      int c = tid + 256 * i;                                                       \
      int row = c >> 4, c4 = c & 15;                                               \
      av[i] = *(const float4*)&x[(size_t)(m_blk + row) * N_NODES + k0_ + 4 * c4];  \
    }                                                                              \
    _Pragma("unroll") for (int i = 0; i < 8; i++) {                                \
      int c = tid + 256 * i;                                                       \
      const ushort_t* src = (i < 4) ? W1th : W1tl;                                 \
      int cc = c & 1023;                                                           \
      int row = cc >> 3, kc = cc & 7;                                              \
      bv[i] = *(const uint4*)&src[(size_t)row * N_NODES + k0_ + 8 * kc];           \
    }                                                                              \
  }

#define STORE_TILE()                                                               \
  {                                                                                \
    _Pragma("unroll") for (int i = 0; i < 8; i++) {                                \
      int c = tid + 256 * i;                                                       \
      int row = c >> 4, c4 = c & 15;                                               \
      float f0 = av[i].x, f1 = av[i].y, f2 = av[i].z, f3 = av[i].w;                \
      ushort_t h0 = f2bf(f0), h1 = f2bf(f1), h2 = f2bf(f2), h3 = f2bf(f3);         \
      ushort_t l0 = f2bf(f0 - bf2f(h0)), l1 = f2bf(f1 - bf2f(h1));                 \
      ushort_t l2 = f2bf(f2 - bf2f(h2)), l3 = f2bf(f3 - bf2f(h3));                 \
      uint2 hp, lp;                                                                \
      hp.x = (uint_t)h0 | ((uint_t)h1 << 16); hp.y = (uint_t)h2 | ((uint_t)h3 << 16); \
      lp.x = (uint_t)l0 | ((uint_t)l1 << 16); lp.y = (uint_t)l2 | ((uint_t)l3 << 16); \
      uint_t off = row * 128 + ((c4 * 8) ^ ((row & 7) << 4));                      \
      *(uint2*)(lds + LDSA_H + off) = hp;                                          \
      *(uint2*)(lds + LDSA_L + off) = lp;                                          \
    }                                                                              \
    _Pragma("unroll") for (int i = 0; i < 8; i++) {                                \
      int c = tid + 256 * i;                                                       \
      int base = (i < 4) ? LDSB_H : LDSB_L;                                        \
      int cc = c & 1023;                                                           \
      int row = cc >> 3, kc = cc & 7;                                              \
      uint_t off = row * 128 + ((kc * 16) ^ ((row & 7) << 4));                     \
      *(uint4*)(lds + base + off) = bv[i];                                         \
    }                                                                              \
  }

  // prologue: stage tile 0 (latency exposed once)
  LOAD_TILE(0);
  STORE_TILE();
  __syncthreads();

  for (int kt = 0; kt < ktiles; ++kt) {
    int ktn = (kt + 1 < ktiles) ? kt + 1 : kt;  // clamp (last iter loads are dead)
    // issue next tile's global loads; results consumed only after the barrier,
    // so they stay in flight across the whole MFMA phase (T14).
    LOAD_TILE(ktn);
    // -------- compute on current LDS tile --------
#pragma unroll
    for (int ks = 0; ks < 2; ++ks) {
      int cb = ks * 64 + kb0;
      bfrag bh[4], bl[4];
#pragma unroll
      for (int ni = 0; ni < 4; ni++) {
        int brow = wc * 64 + ni * 16 + lrow;
        uint_t boff = brow * 128 + (cb ^ xr);
        bh[ni] = *(const bfrag*)(lds + LDSB_H + boff);
        bl[ni] = *(const bfrag*)(lds + LDSB_L + boff);
      }
#pragma unroll
      for (int mi = 0; mi < 4; mi++) {
        int arow = wr * 64 + mi * 16 + lrow;
        uint_t aoff = arow * 128 + (cb ^ xr);
        bfrag ah = *(const bfrag*)(lds + LDSA_H + aoff);
        bfrag al = *(const bfrag*)(lds + LDSA_L + aoff);
#pragma unroll
        for (int ni = 0; ni < 4; ni++) {
          acc[mi][ni] = __builtin_amdgcn_mfma_f32_16x16x32_bf16(ah, bh[ni], acc[mi][ni], 0, 0, 0);
          acc[mi][ni] = __builtin_amdgcn_mfma_f32_16x16x32_bf16(ah, bl[ni], acc[mi][ni], 0, 0, 0);
          acc[mi][ni] = __builtin_amdgcn_mfma_f32_16x16x32_bf16(al, bh[ni], acc[mi][ni], 0, 0, 0);
        }
      }
    }
    __syncthreads();  // all waves done reading this LDS tile
    if (kt + 1 < ktiles) {
      STORE_TILE();   // vmcnt drain happens here (latency already hidden)
      __syncthreads();
    }
  }

  // -------- epilogue: C[row=(lane>>4)*4+r][col=lane&15] per 16x16 frag --------
  float* outp = part + (size_t)blockIdx.y * (N_NODES * F1);
#pragma unroll
  for (int mi = 0; mi < 4; mi++) {
#pragma unroll
    for (int ni = 0; ni < 4; ni++) {
      int col = wc * 64 + ni * 16 + lrow;
#pragma unroll
      for (int r = 0; r < 4; r++) {
        int row = m_blk + wr * 64 + mi * 16 + kgrp * 4 + r;
        outp[(size_t)row * F1 + col] = acc[mi][ni][r];
      }
    }
  }
#undef LOAD_TILE
#undef STORE_TILE
}

// in-place safe: each thread reads all S parts at its index, then writes part[0].
__global__ void reduceS_k(const float* __restrict__ part, float* __restrict__ xw1, int S) {
  int i = blockIdx.x * blockDim.x + threadIdx.x;
  float4 a = ((const float4*)part)[i];
  for (int s = 1; s < S; s++) {
    float4 b = ((const float4*)(part + (size_t)s * N_NODES * F1))[i];
    a.x += b.x; a.y += b.y; a.z += b.z; a.w += b.w;
  }
  ((float4*)xw1)[i] = a;
}

// ---------------- aggregation (gather over CSR) + bias + relu ----------------

template <int F>
__global__ void agg_k(const float* __restrict__ xw, const int* __restrict__ csr,
                      const int* __restrict__ rp, const float* __restrict__ dinv,
                      const float* __restrict__ bias, float* __restrict__ hout) {
  int node = blockIdx.x;
  int f = threadIdx.x;
  __shared__ int sidx[F];
  __shared__ float sdv[F];
  int beg = rp[node], end = rp[node + 1];
  float acc = 0.f;
  for (int base = beg; base < end; base += F) {
    int n = end - base;
    if (n > F) n = F;
    __syncthreads();
    if (f < n) {
      int s = csr[base + f];
      sidx[f] = s;
      sdv[f] = dinv[s];
    }
    __syncthreads();
    for (int i = 0; i < n; i++) acc += xw[(size_t)sidx[i] * F + f] * sdv[i];
  }
  float dv = dinv[node];
  float v = (acc + xw[(size_t)node * F + f] * dv) * dv + bias[f];
  hout[(size_t)node * F + f] = v > 0.f ? v : 0.f;
}

// ---------------- GEMM2: h1[8192,128] @ W2[128,64] ----------------

__global__ __launch_bounds__(256) void gemm2_k(const float* __restrict__ h1,
                                               const float* __restrict__ W2,
                                               float* __restrict__ xw2) {
  __shared__ float W2s[F1 * F2];
  __shared__ float As[16 * F1];
  int tid = threadIdx.x;
  int r0 = blockIdx.x * 16;
#pragma unroll
  for (int j = 0; j < 8; j++)
    ((float4*)W2s)[tid + 256 * j] = ((const float4*)W2)[tid + 256 * j];
#pragma unroll
  for (int j = 0; j < 2; j++)
    ((float4*)As)[tid + 256 * j] = ((const float4*)(h1 + (size_t)r0 * F1))[tid + 256 * j];
  __syncthreads();
  int r = tid >> 4, c4 = tid & 15;
  float4 acc = make_float4(0.f, 0.f, 0.f, 0.f);
#pragma unroll 8
  for (int k = 0; k < F1; k++) {
    float a = As[r * F1 + k];
    float4 bv = *(float4*)&W2s[k * F2 + 4 * c4];
    acc.x += a * bv.x; acc.y += a * bv.y; acc.z += a * bv.z; acc.w += a * bv.w;
  }
  *(float4*)&xw2[(size_t)(r0 + r) * F2 + 4 * c4] = acc;
}

// ---------------- P tables: P[i][0:86]=h2[i]@Wfc[:64], P[i][86:172]=h2[i]@Wfc[64:] ----------------

__global__ void pboth_k(const float* __restrict__ h2, const float* __restrict__ Wfc,
                        float* __restrict__ P) {
  __shared__ float hs[64 * 16];
  int tid = threadIdx.x;  // 192
  int r0 = blockIdx.x * 16;
  for (int idx = tid; idx < 256; idx += 192) {
    int row = idx >> 4, k4 = idx & 15;
    float4 h = *(const float4*)&h2[(size_t)(r0 + row) * F2 + 4 * k4];
    hs[(4 * k4 + 0) * 16 + row] = h.x;
    hs[(4 * k4 + 1) * 16 + row] = h.y;
    hs[(4 * k4 + 2) * 16 + row] = h.z;
    hs[(4 * k4 + 3) * 16 + row] = h.w;
  }
  __syncthreads();
  if (tid < 172) {
    int half = tid < 86 ? 0 : 1;
    int j = tid - 86 * half;
    const float* wp = Wfc + (size_t)(64 * half) * N_TYPES + j;
    float acc[16];
#pragma unroll
    for (int r = 0; r < 16; r++) acc[r] = 0.f;
    for (int k = 0; k < 64; k++) {
      float w = wp[(size_t)k * N_TYPES];
      const float* hk = &hs[k * 16];
#pragma unroll
      for (int r = 0; r < 16; r++) acc[r] += hk[r] * w;
    }
#pragma unroll
    for (int r = 0; r < 16; r++) P[(size_t)(r0 + r) * 172 + tid] = acc[r];
  }
}

// ---------------- final: out[p][t] = sigmoid(P1[d1[p]][t] + P2[d2[p]][t] + bfc[t]) ----------------

__global__ void final_k(const float* __restrict__ P, const int* __restrict__ d1,
                        const int* __restrict__ d2, const float* __restrict__ bfc,
                        float* __restrict__ out) {
  int gid = blockIdx.x * blockDim.x + threadIdx.x;
  if (gid >= N_PAIRS * 43) return;
  int p = gid / 43;
  int j = gid - p * 43;
  int a = d1[p], b = d2[p];
  float2 v1 = *(const float2*)&P[(size_t)a * 172 + 2 * j];
  float2 v2 = *(const float2*)&P[(size_t)b * 172 + 86 + 2 * j];
  float2 bb = *(const float2*)&bfc[2 * j];
  float z0 = v1.x + v2.x + bb.x;
  float z1 = v1.y + v2.y + bb.y;
  float2 o;
  o.x = 1.0f / (1.0f + expf(-z0));
  o.y = 1.0f / (1.0f + expf(-z1));
  *(float2*)&out[(size_t)p * 86 + 2 * j] = o;
}

// ---------------- launch ----------------

extern "C" void kernel_launch(void* const* d_in, const int* in_sizes, int n_in,
                              void* d_out, int out_size, void* d_ws, size_t ws_size,
                              hipStream_t stream) {
  const float* x   = (const float*)d_in[0];
  const int*   ei  = (const int*)d_in[1];
  const int*   d1  = (const int*)d_in[2];
  const int*   d2  = (const int*)d_in[3];
  const float* W1  = (const float*)d_in[4];
  const float* b1  = (const float*)d_in[5];
  const float* W2  = (const float*)d_in[6];
  const float* b2  = (const float*)d_in[7];
  const float* Wfc = (const float*)d_in[8];
  const float* bfc = (const float*)d_in[9];
  float* out = (float*)d_out;

  const int* esrc = ei;
  const int* edst = ei + N_EDGES;

  char* w = (char*)d_ws;
  size_t off = 0;
  auto alloc = [&](size_t bytes) -> char* {
    char* p = w + off;
    off += (bytes + 255) & ~(size_t)255;
    return p;
  };
  int*      cnt  = (int*)alloc((size_t)N_NODES * 4);
  float*    dinv = (float*)alloc((size_t)N_NODES * 4);
  int*      rp   = (int*)alloc((size_t)(N_NODES + 1) * 4);
  int*      fill = (int*)alloc((size_t)N_NODES * 4);
  int*      csr  = (int*)alloc((size_t)N_EDGES * 4);
  ushort_t* W1th = (ushort_t*)alloc((size_t)N_NODES * F1 * 2);
  ushort_t* W1tl = (ushort_t*)alloc((size_t)N_NODES * F1 * 2);
  float*    h1   = (float*)alloc((size_t)N_NODES * F1 * 4);
  float*    xw2  = (float*)alloc((size_t)N_NODES * F2 * 4);
  float*    h2   = (float*)alloc((size_t)N_NODES * F2 * 4);
  float*    P    = (float*)alloc((size_t)N_NODES * 172 * 4);

  size_t partBytes = (size_t)N_NODES * F1 * 4;
  int S = 8;
  while (S > 1 && off + (size_t)S * partBytes > ws_size) S >>= 1;
  float* part = (float*)alloc((size_t)S * partBytes);
  float* xw1 = part;  // alias; reduceS_k is index-aligned in-place safe
  if (off > ws_size) return;

  hipMemsetAsync(cnt, 0, (size_t)N_NODES * 4, stream);
  count_deg_k<<<N_EDGES / 256, 256, 0, stream>>>(edst, cnt);
  dinv_k<<<N_NODES / 256, 256, 0, stream>>>(cnt, dinv);
  scan_k<<<1, 1024, 0, stream>>>(cnt, rp, fill);
  scatter_k<<<N_EDGES / 256, 256, 0, stream>>>(esrc, edst, fill, csr);

  w1split_k<<<dim3(N_NODES / 64, F1 / 32), 256, 0, stream>>>(W1, W1th, W1tl);
  gemm1_mfma_k<<<dim3(N_NODES / 128, S), 256, 0, stream>>>(x, W1th, W1tl, part, N_NODES / S);
  if (S > 1)
    reduceS_k<<<(N_NODES * F1 / 4) / 256, 256, 0, stream>>>(part, xw1, S);
  agg_k<F1><<<N_NODES, F1, 0, stream>>>(xw1, csr, rp, dinv, b1, h1);

  gemm2_k<<<N_NODES / 16, 256, 0, stream>>>(h1, W2, xw2);
  agg_k<F2><<<N_NODES, F2, 0, stream>>>(xw2, csr, rp, dinv, b2, h2);

  pboth_k<<<N_NODES / 16, 192, 0, stream>>>(h2, Wfc, P);
  final_k<<<(N_PAIRS * 43) / 256, 256, 0, stream>>>(P, d1, d2, bfc, out);
}

// Round 5
// 267.656 us; speedup vs baseline: 2.2866x; 1.2949x over previous
//
#include <hip/hip_runtime.h>
#include <math.h>
#include <stdint.h>
#include <stddef.h>

#define N_NODES 8192
#define N_EDGES 524288
#define N_PAIRS 262144
#define N_TYPES 86
#define F1 128
#define F2 64

typedef unsigned short ushort_t;
typedef unsigned int uint_t;
typedef __attribute__((ext_vector_type(8))) short bfrag;
typedef __attribute__((ext_vector_type(4))) float ffrag;

typedef __attribute__((address_space(3))) char lds_char;
typedef __attribute__((address_space(1))) const char g_char;

__device__ __forceinline__ void gload16(const void* g, void* l) {
  // 16B global -> LDS direct (dest = wave-uniform base + lane*16)
  __builtin_amdgcn_global_load_lds((const g_char*)g, (lds_char*)l, 16, 0, 0);
}

__device__ inline ushort_t f2bf(float f) {
  uint_t u = __float_as_uint(f);
  uint_t r = u + 0x7fffu + ((u >> 16) & 1u);
  return (ushort_t)(r >> 16);
}
__device__ inline float bf2f(ushort_t h) {
  return __uint_as_float(((uint_t)h) << 16);
}

// ---------------- degree / CSR build ----------------

__global__ void count_deg_k(const int* __restrict__ dst, int* __restrict__ cnt) {
  int e = blockIdx.x * blockDim.x + threadIdx.x;
  if (e < N_EDGES) atomicAdd(&cnt[dst[e]], 1);
}

__global__ void dinv_k(const int* __restrict__ cnt, float* __restrict__ dinv) {
  int i = blockIdx.x * blockDim.x + threadIdx.x;
  if (i < N_NODES) dinv[i] = 1.0f / sqrtf((float)(cnt[i] + 1)); // +1 self-loop
}

__global__ void scan_k(const int* __restrict__ cnt, int* __restrict__ rp,
                       int* __restrict__ fill) {
  __shared__ int s[1024];
  int t = threadIdx.x;
  int v[8];
  int sum = 0;
#pragma unroll
  for (int i = 0; i < 8; i++) { v[i] = cnt[t * 8 + i]; sum += v[i]; }
  s[t] = sum;
  __syncthreads();
  for (int off = 1; off < 1024; off <<= 1) {
    int add = (t >= off) ? s[t - off] : 0;
    __syncthreads();
    s[t] += add;
    __syncthreads();
  }
  int excl = s[t] - sum;
#pragma unroll
  for (int i = 0; i < 8; i++) {
    rp[t * 8 + i] = excl;
    fill[t * 8 + i] = excl;
    excl += v[i];
  }
  if (t == 1023) rp[N_NODES] = excl;
}

__global__ void scatter_k(const int* __restrict__ src, const int* __restrict__ dst,
                          int* fill, int* __restrict__ csr) {
  int e = blockIdx.x * blockDim.x + threadIdx.x;
  if (e < N_EDGES) {
    int d = dst[e];
    int pos = atomicAdd(&fill[d], 1);
    csr[pos] = src[e];
  }
}

// ---------------- W1 split + transpose: W1th/W1tl[n][k] = hi/lo(W1[k][n]) ----------------

__global__ __launch_bounds__(256) void w1split_k(const float* __restrict__ W1,
                                                 ushort_t* __restrict__ W1th,
                                                 ushort_t* __restrict__ W1tl) {
  __shared__ ushort_t lh[32 * 65];
  __shared__ ushort_t ll[32 * 65];
  int tid = threadIdx.x;
  int k0 = blockIdx.x * 64;
  int n0 = blockIdx.y * 32;
#pragma unroll
  for (int i = 0; i < 8; i++) {
    int c = tid + 256 * i;
    int kr = c >> 5, nc = c & 31;
    float v = W1[(size_t)(k0 + kr) * F1 + n0 + nc];
    ushort_t h = f2bf(v);
    ushort_t l = f2bf(v - bf2f(h));
    lh[nc * 65 + kr] = h;
    ll[nc * 65 + kr] = l;
  }
  __syncthreads();
#pragma unroll
  for (int i = 0; i < 2; i++) {
    int c = tid + 256 * i;
    int buf = c >> 8;
    int cc = c & 255;
    int nr = cc >> 3, kc = cc & 7;
    const ushort_t* l = buf ? ll : lh;
    uint4 u;
    u.x = (uint_t)l[nr * 65 + kc * 8 + 0] | ((uint_t)l[nr * 65 + kc * 8 + 1] << 16);
    u.y = (uint_t)l[nr * 65 + kc * 8 + 2] | ((uint_t)l[nr * 65 + kc * 8 + 3] << 16);
    u.z = (uint_t)l[nr * 65 + kc * 8 + 4] | ((uint_t)l[nr * 65 + kc * 8 + 5] << 16);
    u.w = (uint_t)l[nr * 65 + kc * 8 + 6] | ((uint_t)l[nr * 65 + kc * 8 + 7] << 16);
    ushort_t* dst = (buf ? W1tl : W1th) + (size_t)(n0 + nr) * N_NODES + k0 + kc * 8;
    *(uint4*)dst = u;
  }
}

// ---------------- GEMM1 (MFMA split-bf16 3-term, 2-phase dbuf + gload_lds B) --------
// 512 thr (8 waves 2x4), BM=128, BN=128, BK=64, K-split S; LDS 2 x 64KB.
// Buffer layout: [AH 16K][AL 16K][BH 16K][BL 16K]; A XOR-swizzled on write/read,
// B swizzle realized by pre-swizzled per-lane GLOBAL addresses + linear LDS dest.

#define BUFSZ 65536
#define OA_H 0
#define OA_L 16384
#define OB_H 32768
#define OB_L 49152

__global__ __launch_bounds__(512) void gemm1_mfma_k(const float* __restrict__ x,
                                                    const ushort_t* __restrict__ W1th,
                                                    const ushort_t* __restrict__ W1tl,
                                                    float* __restrict__ part, int kspan) {
  __shared__ __align__(16) char lds[2 * BUFSZ];
  int tid = threadIdx.x;
  int m_blk = blockIdx.x * 128;
  int kbase = blockIdx.y * kspan;
  int ktiles = kspan >> 6;
  int wave = tid >> 6, lane = tid & 63;
  int wr = wave >> 2, wc = wave & 3;
  int lrow = lane & 15, kgrp = lane >> 4;
  int xr = (lrow & 7) << 4;
  int kb0 = kgrp * 16;

  // B gload constants: wave covers 4KB quarter of BH (waves 0-3) or BL (4-7)
  const ushort_t* bsrc = (wave < 4) ? W1th : W1tl;
  int b_quarter = (wave & 3) * 4096;
  int ob = (wave < 4) ? OB_H : OB_L;
  int brow_g = (wave & 3) * 32 + (lane >> 3);            // + i*8
  int kel = (((lane & 7) ^ ((lane >> 3) & 7)) << 3);     // pre-swizzled k-elem offset

  ffrag acc[4][2];
#pragma unroll
  for (int mi = 0; mi < 4; mi++)
#pragma unroll
    for (int ni = 0; ni < 2; ni++) acc[mi][ni] = (ffrag)(0.0f);

  float4 av[4];  // A staging (16 VGPR)

#define LOADA(K0)                                                                    \
  {                                                                                  \
    _Pragma("unroll") for (int i = 0; i < 4; i++) {                                  \
      int c = tid + 512 * i;                                                         \
      int row = c >> 4, c4 = c & 15;                                                 \
      av[i] = *(const float4*)&x[(size_t)(m_blk + row) * N_NODES + (K0) + 4 * c4];   \
    }                                                                                \
  }

#define LOADB(K0, BUFP)                                                              \
  {                                                                                  \
    _Pragma("unroll") for (int i = 0; i < 4; i++) {                                  \
      const ushort_t* gp = bsrc + (size_t)(brow_g + i * 8) * N_NODES + (K0) + kel;   \
      gload16(gp, (BUFP) + ob + b_quarter + i * 1024);                               \
    }                                                                                \
  }

#define STOREA(BUFP)                                                                 \
  {                                                                                  \
    _Pragma("unroll") for (int i = 0; i < 4; i++) {                                  \
      int c = tid + 512 * i;                                                         \
      int row = c >> 4, c4 = c & 15;                                                 \
      float f0 = av[i].x, f1 = av[i].y, f2 = av[i].z, f3 = av[i].w;                  \
      ushort_t h0 = f2bf(f0), h1 = f2bf(f1), h2 = f2bf(f2), h3 = f2bf(f3);           \
      ushort_t l0 = f2bf(f0 - bf2f(h0)), l1 = f2bf(f1 - bf2f(h1));                   \
      ushort_t l2 = f2bf(f2 - bf2f(h2)), l3 = f2bf(f3 - bf2f(h3));                   \
      uint2 hp, lp;                                                                  \
      hp.x = (uint_t)h0 | ((uint_t)h1 << 16); hp.y = (uint_t)h2 | ((uint_t)h3 << 16);\
      lp.x = (uint_t)l0 | ((uint_t)l1 << 16); lp.y = (uint_t)l2 | ((uint_t)l3 << 16);\
      uint_t off = row * 128 + ((c4 * 8) ^ ((row & 7) << 4));                        \
      *(uint2*)((BUFP) + OA_H + off) = hp;                                           \
      *(uint2*)((BUFP) + OA_L + off) = lp;                                           \
    }                                                                                \
  }

#define COMPUTE(BUFP)                                                                \
  {                                                                                  \
    _Pragma("unroll") for (int ks = 0; ks < 2; ++ks) {                               \
      int cb = ks * 64 + kb0;                                                        \
      bfrag bh[2], bl[2];                                                            \
      _Pragma("unroll") for (int ni = 0; ni < 2; ni++) {                             \
        int brow = wc * 32 + ni * 16 + lrow;                                         \
        uint_t boff = brow * 128 + (cb ^ xr);                                        \
        bh[ni] = *(const bfrag*)((BUFP) + OB_H + boff);                              \
        bl[ni] = *(const bfrag*)((BUFP) + OB_L + boff);                              \
      }                                                                              \
      _Pragma("unroll") for (int mi = 0; mi < 4; mi++) {                             \
        int arow = wr * 64 + mi * 16 + lrow;                                         \
        uint_t aoff = arow * 128 + (cb ^ xr);                                        \
        bfrag ah = *(const bfrag*)((BUFP) + OA_H + aoff);                            \
        bfrag al = *(const bfrag*)((BUFP) + OA_L + aoff);                            \
        _Pragma("unroll") for (int ni = 0; ni < 2; ni++) {                           \
          acc[mi][ni] = __builtin_amdgcn_mfma_f32_16x16x32_bf16(ah, bh[ni], acc[mi][ni], 0, 0, 0); \
          acc[mi][ni] = __builtin_amdgcn_mfma_f32_16x16x32_bf16(ah, bl[ni], acc[mi][ni], 0, 0, 0); \
          acc[mi][ni] = __builtin_amdgcn_mfma_f32_16x16x32_bf16(al, bh[ni], acc[mi][ni], 0, 0, 0); \
        }                                                                            \
      }                                                                              \
    }                                                                                \
  }

  // prologue: stage tile 0 into buffer 0
  LOADA(kbase);
  LOADB(kbase, lds);
  STOREA(lds);
  __syncthreads();  // drains B gloads + A writes

  int cur = 0;
  for (int kt = 0; kt < ktiles - 1; ++kt) {
    char* bufC = lds + cur * BUFSZ;
    char* bufN = lds + (cur ^ 1) * BUFSZ;
    int k0n = kbase + ((kt + 1) << 6);
    // issue next tile: A->regs first (so A-wait later leaves B in flight), then B->LDS
    LOADA(k0n);
    LOADB(k0n, bufN);
    __builtin_amdgcn_sched_barrier(0);  // pin: loads issued before compute
    COMPUTE(bufC);
    STOREA(bufN);      // vmcnt wait for av here (hidden under compute)
    __syncthreads();   // drains B gloads; all waves done reading bufC
    cur ^= 1;
  }
  COMPUTE(lds + cur * BUFSZ);

  // -------- epilogue: C[row=(lane>>4)*4+r][col=lane&15] per 16x16 frag --------
  float* outp = part + (size_t)blockIdx.y * (N_NODES * F1);
#pragma unroll
  for (int mi = 0; mi < 4; mi++) {
#pragma unroll
    for (int ni = 0; ni < 2; ni++) {
      int col = wc * 32 + ni * 16 + lrow;
#pragma unroll
      for (int r = 0; r < 4; r++) {
        int row = m_blk + wr * 64 + mi * 16 + kgrp * 4 + r;
        outp[(size_t)row * F1 + col] = acc[mi][ni][r];
      }
    }
  }
#undef LOADA
#undef LOADB
#undef STOREA
#undef COMPUTE
}

// in-place safe: each thread reads all S parts at its index, then writes part[0].
__global__ void reduceS_k(const float* __restrict__ part, float* __restrict__ xw1, int S) {
  int i = blockIdx.x * blockDim.x + threadIdx.x;
  float4 a = ((const float4*)part)[i];
  for (int s = 1; s < S; s++) {
    float4 b = ((const float4*)(part + (size_t)s * N_NODES * F1))[i];
    a.x += b.x; a.y += b.y; a.z += b.z; a.w += b.w;
  }
  ((float4*)xw1)[i] = a;
}

// ---------------- aggregation (gather over CSR) + bias + relu ----------------

template <int F>
__global__ void agg_k(const float* __restrict__ xw, const int* __restrict__ csr,
                      const int* __restrict__ rp, const float* __restrict__ dinv,
                      const float* __restrict__ bias, float* __restrict__ hout) {
  int node = blockIdx.x;
  int f = threadIdx.x;
  __shared__ int sidx[F];
  __shared__ float sdv[F];
  int beg = rp[node], end = rp[node + 1];
  float acc = 0.f;
  for (int base = beg; base < end; base += F) {
    int n = end - base;
    if (n > F) n = F;
    __syncthreads();
    if (f < n) {
      int s = csr[base + f];
      sidx[f] = s;
      sdv[f] = dinv[s];
    }
    __syncthreads();
    for (int i = 0; i < n; i++) acc += xw[(size_t)sidx[i] * F + f] * sdv[i];
  }
  float dv = dinv[node];
  float v = (acc + xw[(size_t)node * F + f] * dv) * dv + bias[f];
  hout[(size_t)node * F + f] = v > 0.f ? v : 0.f;
}

// ---------------- GEMM2: h1[8192,128] @ W2[128,64] ----------------

__global__ __launch_bounds__(256) void gemm2_k(const float* __restrict__ h1,
                                               const float* __restrict__ W2,
                                               float* __restrict__ xw2) {
  __shared__ float W2s[F1 * F2];
  __shared__ float As[16 * F1];
  int tid = threadIdx.x;
  int r0 = blockIdx.x * 16;
#pragma unroll
  for (int j = 0; j < 8; j++)
    ((float4*)W2s)[tid + 256 * j] = ((const float4*)W2)[tid + 256 * j];
#pragma unroll
  for (int j = 0; j < 2; j++)
    ((float4*)As)[tid + 256 * j] = ((const float4*)(h1 + (size_t)r0 * F1))[tid + 256 * j];
  __syncthreads();
  int r = tid >> 4, c4 = tid & 15;
  float4 acc = make_float4(0.f, 0.f, 0.f, 0.f);
#pragma unroll 8
  for (int k = 0; k < F1; k++) {
    float a = As[r * F1 + k];
    float4 bv = *(float4*)&W2s[k * F2 + 4 * c4];
    acc.x += a * bv.x; acc.y += a * bv.y; acc.z += a * bv.z; acc.w += a * bv.w;
  }
  *(float4*)&xw2[(size_t)(r0 + r) * F2 + 4 * c4] = acc;
}

// ---------------- P tables: P[i][0:86]=h2[i]@Wfc[:64], P[i][86:172]=h2[i]@Wfc[64:] ----------------

__global__ void pboth_k(const float* __restrict__ h2, const float* __restrict__ Wfc,
                        float* __restrict__ P) {
  __shared__ float hs[64 * 16];
  int tid = threadIdx.x;  // 192
  int r0 = blockIdx.x * 16;
  for (int idx = tid; idx < 256; idx += 192) {
    int row = idx >> 4, k4 = idx & 15;
    float4 h = *(const float4*)&h2[(size_t)(r0 + row) * F2 + 4 * k4];
    hs[(4 * k4 + 0) * 16 + row] = h.x;
    hs[(4 * k4 + 1) * 16 + row] = h.y;
    hs[(4 * k4 + 2) * 16 + row] = h.z;
    hs[(4 * k4 + 3) * 16 + row] = h.w;
  }
  __syncthreads();
  if (tid < 172) {
    int half = tid < 86 ? 0 : 1;
    int j = tid - 86 * half;
    const float* wp = Wfc + (size_t)(64 * half) * N_TYPES + j;
    float acc[16];
#pragma unroll
    for (int r = 0; r < 16; r++) acc[r] = 0.f;
    for (int k = 0; k < 64; k++) {
      float w = wp[(size_t)k * N_TYPES];
      const float* hk = &hs[k * 16];
#pragma unroll
      for (int r = 0; r < 16; r++) acc[r] += hk[r] * w;
    }
#pragma unroll
    for (int r = 0; r < 16; r++) P[(size_t)(r0 + r) * 172 + tid] = acc[r];
  }
}

// ---------------- final: out[p][t] = sigmoid(P1[d1[p]][t] + P2[d2[p]][t] + bfc[t]) ----------------

__global__ void final_k(const float* __restrict__ P, const int* __restrict__ d1,
                        const int* __restrict__ d2, const float* __restrict__ bfc,
                        float* __restrict__ out) {
  int gid = blockIdx.x * blockDim.x + threadIdx.x;
  if (gid >= N_PAIRS * 43) return;
  int p = gid / 43;
  int j = gid - p * 43;
  int a = d1[p], b = d2[p];
  float2 v1 = *(const float2*)&P[(size_t)a * 172 + 2 * j];
  float2 v2 = *(const float2*)&P[(size_t)b * 172 + 86 + 2 * j];
  float2 bb = *(const float2*)&bfc[2 * j];
  float z0 = v1.x + v2.x + bb.x;
  float z1 = v1.y + v2.y + bb.y;
  float2 o;
  o.x = 1.0f / (1.0f + expf(-z0));
  o.y = 1.0f / (1.0f + expf(-z1));
  *(float2*)&out[(size_t)p * 86 + 2 * j] = o;
}

// ---------------- launch ----------------

extern "C" void kernel_launch(void* const* d_in, const int* in_sizes, int n_in,
                              void* d_out, int out_size, void* d_ws, size_t ws_size,
                              hipStream_t stream) {
  const float* x   = (const float*)d_in[0];
  const int*   ei  = (const int*)d_in[1];
  const int*   d1  = (const int*)d_in[2];
  const int*   d2  = (const int*)d_in[3];
  const float* W1  = (const float*)d_in[4];
  const float* b1  = (const float*)d_in[5];
  const float* W2  = (const float*)d_in[6];
  const float* b2  = (const float*)d_in[7];
  const float* Wfc = (const float*)d_in[8];
  const float* bfc = (const float*)d_in[9];
  float* out = (float*)d_out;

  const int* esrc = ei;
  const int* edst = ei + N_EDGES;

  char* w = (char*)d_ws;
  size_t off = 0;
  auto alloc = [&](size_t bytes) -> char* {
    char* p = w + off;
    off += (bytes + 255) & ~(size_t)255;
    return p;
  };
  int*      cnt  = (int*)alloc((size_t)N_NODES * 4);
  float*    dinv = (float*)alloc((size_t)N_NODES * 4);
  int*      rp   = (int*)alloc((size_t)(N_NODES + 1) * 4);
  int*      fill = (int*)alloc((size_t)N_NODES * 4);
  int*      csr  = (int*)alloc((size_t)N_EDGES * 4);
  ushort_t* W1th = (ushort_t*)alloc((size_t)N_NODES * F1 * 2);
  ushort_t* W1tl = (ushort_t*)alloc((size_t)N_NODES * F1 * 2);
  float*    h1   = (float*)alloc((size_t)N_NODES * F1 * 4);
  float*    xw2  = (float*)alloc((size_t)N_NODES * F2 * 4);
  float*    h2   = (float*)alloc((size_t)N_NODES * F2 * 4);
  float*    P    = (float*)alloc((size_t)N_NODES * 172 * 4);

  size_t partBytes = (size_t)N_NODES * F1 * 4;
  int S = 4;
  while (S > 1 && off + (size_t)S * partBytes > ws_size) S >>= 1;
  float* part = (float*)alloc((size_t)S * partBytes);
  float* xw1 = part;  // alias; reduceS_k is index-aligned in-place safe
  if (off > ws_size) return;

  hipMemsetAsync(cnt, 0, (size_t)N_NODES * 4, stream);
  count_deg_k<<<N_EDGES / 256, 256, 0, stream>>>(edst, cnt);
  dinv_k<<<N_NODES / 256, 256, 0, stream>>>(cnt, dinv);
  scan_k<<<1, 1024, 0, stream>>>(cnt, rp, fill);
  scatter_k<<<N_EDGES / 256, 256, 0, stream>>>(esrc, edst, fill, csr);

  w1split_k<<<dim3(N_NODES / 64, F1 / 32), 256, 0, stream>>>(W1, W1th, W1tl);
  gemm1_mfma_k<<<dim3(N_NODES / 128, S), 512, 0, stream>>>(x, W1th, W1tl, part, N_NODES / S);
  if (S > 1)
    reduceS_k<<<(N_NODES * F1 / 4) / 256, 256, 0, stream>>>(part, xw1, S);
  agg_k<F1><<<N_NODES, F1, 0, stream>>>(xw1, csr, rp, dinv, b1, h1);

  gemm2_k<<<N_NODES / 16, 256, 0, stream>>>(h1, W2, xw2);
  agg_k<F2><<<N_NODES, F2, 0, stream>>>(xw2, csr, rp, dinv, b2, h2);

  pboth_k<<<N_NODES / 16, 192, 0, stream>>>(h2, Wfc, P);
  final_k<<<(N_PAIRS * 43) / 256, 256, 0, stream>>>(P, d1, d2, bfc, out);
}